// Round 11
// baseline (199.097 us; speedup 1.0000x reference)
//
#include <hip/hip_runtime.h>
#include <cstdint>
#include <cstring>

#define B_ 32
#define N_ 128
#define F_ 128
#define SPLIT_ 8

typedef __attribute__((ext_vector_type(8))) __bf16 bf16x8;
typedef __attribute__((ext_vector_type(4))) float f32x4;

__device__ inline uint16_t f2bf_bits(float f) {
  __bf16 h = (__bf16)f;
  uint16_t u;
  __builtin_memcpy(&u, &h, 2);
  return u;
}

// async global->LDS, 16B per lane; LDS dst is wave-uniform base (HW adds
// lane*16); GLOBAL src is PER-LANE (must include lane offset!)
__device__ inline void gld16(const float* src, float* dst) {
  __builtin_amdgcn_global_load_lds(
      (const __attribute__((address_space(1))) unsigned int*)src,
      (__attribute__((address_space(3))) unsigned int*)dst, 16, 0, 0);
}

// ---------------- Kernel A: e_v = v_in @ W_ev + b_ev  -> ws ----------------
__global__ __launch_bounds__(128) void ev_kernel(const float* __restrict__ v_in,
                                                 const float* __restrict__ W_ev,
                                                 const float* __restrict__ b_ev,
                                                 float* __restrict__ e_v) {
  __shared__ float vr[8][F_];
  const int R0 = blockIdx.x * 8;
  const int tid = threadIdx.x;  // output feature g
#pragma unroll
  for (int i = 0; i < 8; ++i) vr[i][tid] = v_in[(size_t)(R0 + i) * F_ + tid];
  __syncthreads();
  float acc[8];
  const float bb = b_ev[tid];
#pragma unroll
  for (int i = 0; i < 8; ++i) acc[i] = bb;
  for (int f = 0; f < F_; ++f) {
    const float wv = W_ev[f * F_ + tid];
#pragma unroll
    for (int i = 0; i < 8; ++i) acc[i] += vr[i][f] * wv;
  }
#pragma unroll
  for (int i = 0; i < 8; ++i) e_v[(size_t)(R0 + i) * F_ + tid] = acc[i];
}

// ------- Kernel P: pack W_e (fp32 [128][128]) into bf16 MFMA fragments ------
// Tile t = kt*8+gt. Lane l holds 8 bf16: W_e[kt*32 + 8*(l>>4) + e][gt*16 + (l&15)].
__global__ void pack_kernel(const float* __restrict__ W_e, uint32_t* __restrict__ wp) {
  const int idx = blockIdx.x * 256 + threadIdx.x;  // 0..2047
  const int t = idx >> 6, l = idx & 63;
  const int kt = t >> 3, gt = t & 7;
  const int kbase = kt * 32 + ((l >> 4) << 3);
  const int g = gt * 16 + (l & 15);
#pragma unroll
  for (int p = 0; p < 4; ++p) {
    const uint32_t lo = f2bf_bits(W_e[(kbase + 2 * p) * F_ + g]);
    const uint32_t hi = f2bf_bits(W_e[(kbase + 2 * p + 1) * F_ + g]);
    wp[idx * 4 + p] = lo | (hi << 16);
  }
}

// ---------------- Kernel M: wave-autonomous fused edge GEMM -----------------
// grid = 32(b) * 8(nt) * 4(mc-pair), 128 threads = 2 INDEPENDENT waves.
// Wave w owns m-chunk (mc*2+w)*16 .. +16, computes ALL 128 g for its 16 n.
// W_e fragments in block-shared LDS (32KB, broadcast reads); per-wave A-tile
// (8KB contiguous) double-buffered in private LDS via gld16.  NO in-loop
// barriers: per-wave counted vmcnt, FIFO per iter = [evm 8][gld16 8][st 8],
// full 16-iter unroll (single basic block -> sched_barrier pins issue order).
__global__ __launch_bounds__(128, 1) void main_kernel(
    const float* __restrict__ e_in, const float* __restrict__ e_v,
    const float* __restrict__ b_e, const float* __restrict__ wpf,
    float* __restrict__ e_out, float* __restrict__ pve_part) {
  __shared__ __align__(16) float wlds[8192];        // 32 KB packed W_e
  __shared__ __align__(16) float abuf[2][2][2048];  // [wave][parity][8KB tile]

  const int tid = threadIdx.x;
  const int w = tid >> 6, l = tid & 63;
  const int bid = blockIdx.x;
  const int mc = bid & 3, nt = (bid >> 2) & 7, b = bid >> 5;
  const int n0 = nt * 16;
  const int lr = (l >> 4) << 2;  // g sub-base / D row group
  const int lc = l & 15;         // n within n-tile
  const int m0 = (mc * 2 + w) * 16;
  const int swz = lc & 7;

  const float* einb = e_in + (size_t)b * N_ * N_ * F_;
  const float* evb = e_v + (size_t)b * N_ * F_;

  // loop-invariant col term: evn[gt] = e_v[b][n0+lc][g0] + b_e[g0]
  f32x4 evn[8];
#pragma unroll
  for (int gt = 0; gt < 8; ++gt) {
    const int g0 = gt * 16 + lr;
    evn[gt] = *reinterpret_cast<const f32x4*>(&evb[(size_t)(n0 + lc) * F_ + g0]) +
              *reinterpret_cast<const f32x4*>(&b_e[g0]);
  }

  // stage W into LDS (16 gld16/wave, PER-LANE src = base + l*16B), drain once
#pragma unroll
  for (int q = 0; q < 16; ++q) {
    const int idx = w * 16 + q;
    gld16(wpf + idx * 256 + l * 4, &wlds[idx * 256]);
  }
  asm volatile("s_waitcnt vmcnt(0)" ::: "memory");
  __syncthreads();

  f32x4 pve[8];
#pragma unroll
  for (int gt = 0; gt < 8; ++gt) {
    pve[gt][0] = 0.f; pve[gt][1] = 0.f; pve[gt][2] = 0.f; pve[gt][3] = 0.f;
  }

  f32x4 evm[8];  // single-buffered: consumed (seed) before reload each iter

  // per-wave A stage: 8 gld16, tile = e_in[b][m][n0:n0+16][:] (8KB contig),
  // XOR source swizzle (r&7) so ds_read_b128 fragments are ~conflict-free
#define STAGE(dst, mm)                                              \
  {                                                                 \
    const float* tb_ = einb + ((size_t)(mm) * N_ + n0) * F_;        \
    _Pragma("unroll") for (int k_ = 0; k_ < 8; ++k_) {              \
      const int r_ = k_ * 2 + (l >> 5);                             \
      const int c_ = (l & 31) ^ (r_ & 7);                           \
      gld16(tb_ + r_ * F_ + c_ * 4, &(dst)[k_ * 256]);              \
    }                                                               \
  }
#define EVML(mm)                                                    \
  {                                                                 \
    _Pragma("unroll") for (int gt_ = 0; gt_ < 8; ++gt_) {           \
      evm[gt_] = *reinterpret_cast<const f32x4*>(                   \
          &evb[(size_t)(mm) * F_ + gt_ * 16 + lr]);                 \
    }                                                               \
  }

  // prologue FIFO: [g(0) 8][evm(0) 8][g(1) 8]
  STAGE(abuf[w][0], m0 + 0);
  EVML(m0 + 0);
  STAGE(abuf[w][1], m0 + 1);

#pragma unroll
  for (int it = 0; it < 16; ++it) {
    // wait: retire through evm(it) (and g(it)); newer prefetch+stores fly on
    if (it == 0 || it == 15) {
      asm volatile("s_waitcnt vmcnt(8)" ::: "memory");
    } else {
      asm volatile("s_waitcnt vmcnt(16)" ::: "memory");
    }
    __builtin_amdgcn_sched_barrier(0);

    // seed acc with bias terms (evm consumed HERE, before reload below)
    f32x4 acc[8];
#pragma unroll
    for (int gt = 0; gt < 8; ++gt) acc[gt] = evn[gt] + evm[gt];
    __builtin_amdgcn_sched_barrier(0);

    // A fragments from private LDS + cvt
    const float* fb = abuf[w][it & 1];
    bf16x8 a[4];
#pragma unroll
    for (int kt = 0; kt < 4; ++kt) {
      const int cA = kt * 8 + ((l >> 4) << 1);
      const f32x4 f0 = *reinterpret_cast<const f32x4*>(&fb[lc * 128 + ((cA ^ swz) << 2)]);
      const f32x4 f1 = *reinterpret_cast<const f32x4*>(&fb[lc * 128 + (((cA + 1) ^ swz) << 2)]);
#pragma unroll
      for (int e = 0; e < 4; ++e) {
        a[kt][e] = (__bf16)f0[e];
        a[kt][e + 4] = (__bf16)f1[e];
      }
    }
    asm volatile("s_waitcnt lgkmcnt(0)" ::: "memory");  // A-buf free for reuse
    __builtin_amdgcn_sched_barrier(0);

    // issue next evm then next A-stage (FIFO: evm older than gld16)
    if (it < 15) EVML(m0 + it + 1);
    if (it < 14) STAGE(abuf[w][it & 1], m0 + it + 2);
    __builtin_amdgcn_sched_barrier(0);

    // MFMA: W fragments broadcast from shared LDS
#pragma unroll
    for (int kt = 0; kt < 4; ++kt) {
#pragma unroll
      for (int gt = 0; gt < 8; ++gt) {
        const bf16x8 wf = *reinterpret_cast<const bf16x8*>(
            &wlds[((kt * 8 + gt) * 64 + l) * 4]);
        acc[gt] = __builtin_amdgcn_mfma_f32_16x16x32_bf16(wf, a[kt], acc[gt], 0, 0, 0);
      }
    }

    // epilogue: relu, per_v_e accumulate, store 16n x 128g
    const int m = m0 + it;
    float* op = e_out + (((size_t)(b * N_) + m) * N_ + n0 + lc) * F_;
#pragma unroll
    for (int gt = 0; gt < 8; ++gt) {
      const int g0 = gt * 16 + lr;
      f32x4 v = acc[gt];
#pragma unroll
      for (int q = 0; q < 4; ++q) v[q] = fmaxf(v[q], 0.f);
      pve[gt] += v;
      *reinterpret_cast<f32x4*>(&op[g0]) = v;
    }
    __builtin_amdgcn_sched_barrier(0);
  }
#undef STAGE
#undef EVML

  // wave owns its (chunk, n-slice): write partial per_v_e directly
  const int c = mc * 2 + w;
  float* pp = pve_part + (((size_t)c * B_ + b) * N_ + n0 + lc) * F_;
#pragma unroll
  for (int gt = 0; gt < 8; ++gt)
    *reinterpret_cast<f32x4*>(&pp[gt * 16 + lr]) = pve[gt];
}

// ---------------- Kernel V: v_out = relu([sum(pve), v_in] @ W_v + b_v) ------
__global__ __launch_bounds__(128) void v_kernel(
    const float* __restrict__ v_in, const float* __restrict__ pve_part,
    const float* __restrict__ W_v, const float* __restrict__ b_v,
    float* __restrict__ v_out) {
  __shared__ float rows[8][256];
  const int R0 = blockIdx.x * 8;
  const int tid = threadIdx.x;
#pragma unroll
  for (int i = 0; i < 8; ++i) {
    const size_t r = R0 + i;
    float acc = 0.f;
#pragma unroll
    for (int s = 0; s < SPLIT_; ++s)
      acc += pve_part[((size_t)s * B_ * N_ + r) * F_ + tid];
    rows[i][tid] = acc;
    rows[i][128 + tid] = v_in[r * F_ + tid];
  }
  __syncthreads();
  float acc[8];
  const float bb = b_v[tid];
#pragma unroll
  for (int i = 0; i < 8; ++i) acc[i] = bb;
  for (int f = 0; f < 256; ++f) {
    const float wv = W_v[f * F_ + tid];
#pragma unroll
    for (int i = 0; i < 8; ++i) acc[i] += rows[i][f] * wv;
  }
#pragma unroll
  for (int i = 0; i < 8; ++i)
    v_out[(size_t)(R0 + i) * F_ + tid] = fmaxf(acc[i], 0.f);
}

extern "C" void kernel_launch(void* const* d_in, const int* in_sizes, int n_in,
                              void* d_out, int out_size, void* d_ws, size_t ws_size,
                              hipStream_t stream) {
  const float* v_in = (const float*)d_in[0];
  const float* e_in = (const float*)d_in[1];
  const float* W_ev = (const float*)d_in[2];
  const float* b_ev = (const float*)d_in[3];
  const float* W_e  = (const float*)d_in[4];
  const float* b_e  = (const float*)d_in[5];
  const float* W_v  = (const float*)d_in[6];
  const float* b_v  = (const float*)d_in[7];

  float* out = (float*)d_out;
  float* v_out = out;                         // [32,128,128]
  float* e_out = out + (size_t)B_ * N_ * F_;  // [32,128,128,128]

  char* ws = (char*)d_ws;
  float* e_v = (float*)ws;                                   // 2 MB
  uint32_t* wpack = (uint32_t*)(ws + (size_t)2097152);       // 64 KB slot
  float* pve_part = (float*)(ws + (size_t)2097152 + 65536);  // 16 MB

  ev_kernel<<<(B_ * N_) / 8, 128, 0, stream>>>(v_in, W_ev, b_ev, e_v);
  pack_kernel<<<8, 256, 0, stream>>>(W_e, wpack);
  main_kernel<<<B_ * 8 * 4, 128, 0, stream>>>(e_in, e_v, b_e,
                                              (const float*)wpack,
                                              e_out, pve_part);
  v_kernel<<<(B_ * N_) / 8, 128, 0, stream>>>(v_in, pve_part, W_v, b_v, v_out);
}